// Round 8
// baseline (1171.707 us; speedup 1.0000x reference)
//
#include <hip/hip_runtime.h>
#include <hip/hip_fp16.h>

#define NN 100000
#define EDG 1600000
#define LAY 2
#define NBKT 98      // ceil(NN / 1024)
#define BKTPAD 128
#define CAP 18432    // LDS sort capacity per bucket (avg 16384, ~16 sigma margin)
#define PCHUNK 2560  // edges per partition block (256 thr x 10)
#define CPR 625      // EDG / PCHUNK (exact)

static inline int cdiv(int a, int b) { return (a + b - 1) / b; }

// ---------------- init ----------------
__global__ void k_init(int* bhist, float* stats) {
    int t = blockIdx.x * blockDim.x + threadIdx.x;
    if (t < 4 * BKTPAD) bhist[t] = 0;
    if (t < 4 * 64) stats[t] = 0.f;
}

// ---------------- coarse bucket histogram ----------------
__global__ __launch_bounds__(256) void k_bhist(const int* __restrict__ ll,
                                               const int* __restrict__ hh,
                                               const int* __restrict__ hl,
                                               const int* __restrict__ lh, int* __restrict__ bhist) {
    __shared__ int h[NBKT];
    int tid = threadIdx.x;
    if (tid < NBKT) h[tid] = 0;
    __syncthreads();
    int r = blockIdx.x / CPR;
    int chunk = blockIdx.x - r * CPR;
    const int* dst = (r == 0 ? ll : r == 1 ? hh : r == 2 ? hl : lh) + EDG;
    int base = chunk * PCHUNK;
#pragma unroll
    for (int k = 0; k < 10; k++) {
        int d = dst[base + k * 256 + tid];
        atomicAdd(&h[d >> 10], 1);
    }
    __syncthreads();
    if (tid < NBKT) atomicAdd(&bhist[r * BKTPAD + tid], h[tid]);
}

// ---------------- tiny scan of bucket counts ----------------
__global__ void k_bscan(const int* __restrict__ bhist, int* __restrict__ bases,
                        int* __restrict__ gcursor, int* __restrict__ rp) {
    __shared__ int sh[BKTPAD];
    int t = threadIdx.x;
    for (int r = 0; r < 4; r++) {
        int v = (t < BKTPAD) ? ((t < NBKT) ? bhist[r * BKTPAD + t] : 0) : 0;
        if (t < BKTPAD) sh[t] = v;
        __syncthreads();
        for (int off = 1; off < BKTPAD; off <<= 1) {
            int x = (t < BKTPAD && t >= off) ? sh[t - off] : 0;
            __syncthreads();
            if (t < BKTPAD) sh[t] += x;
            __syncthreads();
        }
        if (t < BKTPAD) {
            int ex = sh[t] - v;
            bases[r * BKTPAD + t] = ex;
            gcursor[r * BKTPAD + t] = ex;
        }
        __syncthreads();
    }
    if (t < 4) rp[t * (NN + 1) + NN] = EDG;
}

// ---------------- partition edges into coarse buckets (coalesced runs) ----------------
__global__ __launch_bounds__(256) void k_partition(const int* __restrict__ ll,
                                                   const int* __restrict__ hh,
                                                   const int* __restrict__ hl,
                                                   const int* __restrict__ lh,
                                                   int* __restrict__ gcursor,
                                                   int2* __restrict__ pairs) {
    __shared__ int lhist[NBKT], lbase[NBKT];
    int tid = threadIdx.x;
    if (tid < NBKT) lhist[tid] = 0;
    __syncthreads();
    int r = blockIdx.x / CPR;
    int chunk = blockIdx.x - r * CPR;
    const int* ei = (r == 0 ? ll : r == 1 ? hh : r == 2 ? hl : lh);
    const int* srcp = ei;
    const int* dstp = ei + EDG;
    int base = chunk * PCHUNK;
    int s[10], d[10], rk[10];
#pragma unroll
    for (int k = 0; k < 10; k++) {
        int e = base + k * 256 + tid;
        s[k] = srcp[e];
        d[k] = dstp[e];
        rk[k] = atomicAdd(&lhist[d[k] >> 10], 1);
    }
    __syncthreads();
    if (tid < NBKT) lbase[tid] = atomicAdd(&gcursor[r * BKTPAD + tid], lhist[tid]);
    __syncthreads();
    int2* pr = pairs + (size_t)r * EDG;
#pragma unroll
    for (int k = 0; k < 10; k++) {
        int b = d[k] >> 10;
        pr[lbase[b] + rk[k]] = make_int2(s[k], d[k]);
    }
}

// ---------------- per-bucket CSR finalize: rowptr + coalesced cs ----------------
__global__ __launch_bounds__(256) void k_build(const int2* __restrict__ pairs,
                                               const int* __restrict__ bases,
                                               const int* __restrict__ bhist, int* __restrict__ rp,
                                               int* __restrict__ cs) {
    __shared__ int cnt_arr[1024];
    __shared__ int sh[256];
    __shared__ int srcs[CAP];
    int tid = threadIdx.x;
    int r = blockIdx.x / NBKT;
    int b = blockIdx.x - r * NBKT;
    int base = bases[r * BKTPAD + b];
    int cnt = bhist[r * BKTPAD + b];
    int d0 = b << 10;
    int ndst = NN - d0;
    if (ndst > 1024) ndst = 1024;
#pragma unroll
    for (int j = 0; j < 4; j++) cnt_arr[4 * tid + j] = 0;
    __syncthreads();
    const int2* pr = pairs + (size_t)r * EDG + base;
    for (int i = tid; i < cnt; i += 256) {
        int2 p = pr[i];
        atomicAdd(&cnt_arr[p.y - d0], 1);
    }
    __syncthreads();
    int c0 = cnt_arr[4 * tid], c1 = cnt_arr[4 * tid + 1], c2 = cnt_arr[4 * tid + 2],
        c3 = cnt_arr[4 * tid + 3];
    int s = c0 + c1 + c2 + c3;
    sh[tid] = s;
    __syncthreads();
    for (int off = 1; off < 256; off <<= 1) {
        int x = (tid >= off) ? sh[tid - off] : 0;
        __syncthreads();
        sh[tid] += x;
        __syncthreads();
    }
    int run = sh[tid] - s;
    int st0 = run, st1 = st0 + c0, st2 = st1 + c1, st3 = st2 + c2;
    cnt_arr[4 * tid] = st0;
    cnt_arr[4 * tid + 1] = st1;
    cnt_arr[4 * tid + 2] = st2;
    cnt_arr[4 * tid + 3] = st3;
    int* rpr = rp + r * (NN + 1);
    if (4 * tid + 0 < ndst) rpr[d0 + 4 * tid + 0] = base + st0;
    if (4 * tid + 1 < ndst) rpr[d0 + 4 * tid + 1] = base + st1;
    if (4 * tid + 2 < ndst) rpr[d0 + 4 * tid + 2] = base + st2;
    if (4 * tid + 3 < ndst) rpr[d0 + 4 * tid + 3] = base + st3;
    __syncthreads();
    for (int i = tid; i < cnt; i += 256) {
        int2 p = pr[i];
        int pos = atomicAdd(&cnt_arr[p.y - d0], 1);
        if (pos < CAP) srcs[pos] = p.x;
    }
    __syncthreads();
    int* csr = cs + (size_t)r * EDG + base;
    for (int i = tid; i < cnt; i += 256) csr[i] = (i < CAP) ? srcs[i] : 0;
}

__global__ void k_dinv(const int* __restrict__ rp, float* __restrict__ dinv_l,
                       float* __restrict__ dinv_h) {
    int i = blockIdx.x * blockDim.x + threadIdx.x;
    if (i >= 2 * NN) return;
    int r = (i < NN) ? 0 : 1, j = (i < NN) ? i : i - NN;
    const int* rpr = rp + r * (NN + 1);
    float deg = (float)(rpr[j + 1] - rpr[j]) + 1.f;
    float v = rsqrtf(deg);
    if (r == 0) dinv_l[j] = v;
    else dinv_h[j] = v;
}

// ---------------- fused (optional BN+ReLU input) 3-output GEMM, y0 pre-scaled by dinv ----------------
__global__ __launch_bounds__(256) void k_gemm3(const float* __restrict__ x,
                                               const float* __restrict__ stats,
                                               const float* __restrict__ gamma,
                                               const float* __restrict__ beta,
                                               const float* __restrict__ W0,
                                               const float* __restrict__ W1,
                                               const float* __restrict__ W2,
                                               const float* __restrict__ scale0,
                                               __half* __restrict__ y0, __half* __restrict__ y1,
                                               __half* __restrict__ y2) {
    __shared__ float Ws[3][1024];
    __shared__ float xs[8][32];
    int tid = threadIdx.x;
    for (int i = tid; i < 1024; i += 256) {
        Ws[0][i] = W0[i];
        Ws[1][i] = W1[i];
        Ws[2][i] = W2[i];
    }
    int c = tid & 31, rl = tid >> 5;
    float mu = 0.f, gs = 1.f, be = 0.f;
    if (stats) {
        const float inv_n = 1.f / (float)NN;
        mu = stats[c] * inv_n;
        float var = stats[32 + c] * inv_n - mu * mu;
        gs = gamma[c] * rsqrtf(var + 1e-5f);
        be = beta[c];
    }
    for (int r0 = blockIdx.x * 8; r0 < NN; r0 += gridDim.x * 8) {
        int r = r0 + rl;
        __syncthreads();
        if (r < NN) {
            float xv = x[(size_t)r * 32 + c];
            if (stats) {
                xv = gs * (xv - mu) + be;
                xv = (xv > 0.f) ? xv : 0.f;
            }
            xs[rl][c] = xv;
        }
        __syncthreads();
        if (r < NN) {
            float a0 = 0.f, a1 = 0.f, a2 = 0.f;
#pragma unroll
            for (int k = 0; k < 32; k++) {
                float xv = xs[rl][k];
                a0 += xv * Ws[0][k * 32 + c];
                a1 += xv * Ws[1][k * 32 + c];
                a2 += xv * Ws[2][k * 32 + c];
            }
            a0 *= scale0[r];
            y0[(size_t)r * 32 + c] = __float2half(a0);
            y1[(size_t)r * 32 + c] = __float2half(a1);
            y2[(size_t)r * 32 + c] = __float2half(a2);
        }
    }
}

// ---------------- fused GCN + GATv2 pull aggregation + BN-stats epilogue ----------------
// 16-lane groups, half2 per lane (2 columns), 8-edge chunks
__global__ __launch_bounds__(256) void k_aggregate(
    const int* __restrict__ rp_gcn, const int* __restrict__ cs_gcn,
    const __half* __restrict__ h_gcn, const float* __restrict__ dinv,
    const int* __restrict__ rp_gat, const int* __restrict__ cs_gat,
    const __half* __restrict__ h_gl, const __half* __restrict__ h_gr,
    const float* __restrict__ attv, const float* __restrict__ b_gcn,
    const float* __restrict__ b_gat, float* __restrict__ out, float* __restrict__ stats) {
    int tid = threadIdx.x;
    int c2 = tid & 15, g = tid >> 4;
    const float2* att2p = (const float2*)attv;
    float2 att2 = att2p[c2];
    float2 bias2;
    bias2.x = b_gcn[2 * c2] + b_gat[2 * c2];
    bias2.y = b_gcn[2 * c2 + 1] + b_gat[2 * c2 + 1];
    const __half2* hg = (const __half2*)h_gcn;
    const __half2* hlp = (const __half2*)h_gl;
    const __half2* hrp = (const __half2*)h_gr;
    float2 s1 = {0.f, 0.f}, s2 = {0.f, 0.f};
    for (int v = blockIdx.x * 16 + g; v < NN; v += gridDim.x * 16) {
        // ---- GCN (rows pre-scaled by dinv[src]) ----
        float2 acc = {0.f, 0.f};
        int b0 = rp_gcn[v], e0 = rp_gcn[v + 1];
        int e = b0;
        for (; e + 8 <= e0; e += 8) {
            int sidx[8];
#pragma unroll
            for (int k = 0; k < 8; k++) sidx[k] = cs_gcn[e + k];
            float2 hv[8];
#pragma unroll
            for (int k = 0; k < 8; k++) hv[k] = __half22float2(hg[(size_t)sidx[k] * 16 + c2]);
#pragma unroll
            for (int k = 0; k < 8; k++) {
                acc.x += hv[k].x;
                acc.y += hv[k].y;
            }
        }
        for (; e < e0; ++e) {
            float2 hv = __half22float2(hg[(size_t)cs_gcn[e] * 16 + c2]);
            acc.x += hv.x;
            acc.y += hv.y;
        }
        float dv = dinv[v];
        float2 hs = __half22float2(hg[(size_t)v * 16 + c2]);
        acc.x = (acc.x + hs.x) * dv;
        acc.y = (acc.y + hs.y) * dv;
        // ---- GATv2 online softmax, 8-edge chunks ----
        float2 hr2 = __half22float2(hrp[(size_t)v * 16 + c2]);
        float m = -3.0e38f, ss = 0.f;
        float2 o = {0.f, 0.f};
        int b1 = rp_gat[v], e1 = rp_gat[v + 1];
        for (int eb = b1; eb < e1; eb += 8) {
            float2 hl[8];
            float p[8];
#pragma unroll
            for (int k = 0; k < 8; k++) {
                bool valid = (eb + k) < e1;
                int sA = cs_gat[valid ? eb + k : b1];
                hl[k] = __half22float2(hlp[(size_t)sA * 16 + c2]);
                float tx = hl[k].x + hr2.x;
                tx = (tx > 0.f) ? tx : 0.2f * tx;
                float ty = hl[k].y + hr2.y;
                ty = (ty > 0.f) ? ty : 0.2f * ty;
                p[k] = valid ? (tx * att2.x + ty * att2.y) : -3.0e38f;
            }
#pragma unroll
            for (int off = 8; off >= 1; off >>= 1) {
#pragma unroll
                for (int k = 0; k < 8; k++) p[k] += __shfl_xor(p[k], off, 16);
            }
            float cmax = p[0];
#pragma unroll
            for (int k = 1; k < 8; k++) cmax = fmaxf(cmax, p[k]);
            float mn = fmaxf(m, cmax);
            float sc = __expf(m - mn);
            float wsum = 0.f;
            float2 oa = {0.f, 0.f};
#pragma unroll
            for (int k = 0; k < 8; k++) {
                float w = __expf(p[k] - mn);
                wsum += w;
                oa.x += w * hl[k].x;
                oa.y += w * hl[k].y;
            }
            ss = ss * sc + wsum;
            o.x = o.x * sc + oa.x;
            o.y = o.y * sc + oa.y;
            m = mn;
        }
        float inv = 1.f / (ss + 1e-16f);
        float2 res;
        res.x = acc.x + o.x * inv + bias2.x;
        res.y = acc.y + o.y * inv + bias2.y;
        ((float2*)out)[(size_t)v * 16 + c2] = res;
        s1.x += res.x;
        s1.y += res.y;
        s2.x += res.x * res.x;
        s2.y += res.y * res.y;
    }
    __shared__ float2 sd[256], sq[256];
    sd[tid] = s1;
    sq[tid] = s2;
    __syncthreads();
    if (tid < 16) {
        float2 a = sd[tid], b = sq[tid];
        for (int k = 1; k < 16; k++) {
            a.x += sd[tid + 16 * k].x;
            a.y += sd[tid + 16 * k].y;
            b.x += sq[tid + 16 * k].x;
            b.y += sq[tid + 16 * k].y;
        }
        atomicAdd(&stats[2 * tid], a.x);
        atomicAdd(&stats[2 * tid + 1], a.y);
        atomicAdd(&stats[32 + 2 * tid], b.x);
        atomicAdd(&stats[32 + 2 * tid + 1], b.y);
    }
}

// ---------------- final BN apply + ReLU (float4) ----------------
__global__ void k_bn_apply(const float* __restrict__ x, const float* __restrict__ stats,
                           const float* __restrict__ gamma, const float* __restrict__ beta,
                           float* __restrict__ y) {
    int total4 = NN * 8;  // NN*32/4
    const float inv_n = 1.f / (float)NN;
    const float4* x4 = (const float4*)x;
    float4* y4 = (float4*)y;
    for (int i = blockIdx.x * blockDim.x + threadIdx.x; i < total4; i += gridDim.x * blockDim.x) {
        int c0 = (i * 4) & 31;
        float4 v = x4[i];
        float r[4] = {v.x, v.y, v.z, v.w};
#pragma unroll
        for (int j = 0; j < 4; j++) {
            int c = c0 + j;
            float mu = stats[c] * inv_n;
            float var = stats[32 + c] * inv_n - mu * mu;
            float gs = gamma[c] * rsqrtf(var + 1e-5f);
            float t = gs * (r[j] - mu) + beta[c];
            r[j] = (t > 0.f) ? t : 0.f;
        }
        y4[i] = make_float4(r[0], r[1], r[2], r[3]);
    }
}

// ---------------- host ----------------
extern "C" void kernel_launch(void* const* d_in, const int* in_sizes, int n_in, void* d_out,
                              int out_size, void* d_ws, size_t ws_size, hipStream_t stream) {
    const float* x_l = (const float*)d_in[0];
    const float* x_h = (const float*)d_in[1];
    const float* Wll = (const float*)d_in[2];
    const float* bll = (const float*)d_in[3];
    const float* Whh = (const float*)d_in[4];
    const float* bhh = (const float*)d_in[5];
    const float* Whl_l = (const float*)d_in[6];
    const float* Whl_r = (const float*)d_in[7];
    const float* att_hl = (const float*)d_in[8];
    const float* b_hl = (const float*)d_in[9];
    const float* Wlh_l = (const float*)d_in[10];
    const float* Wlh_r = (const float*)d_in[11];
    const float* att_lh = (const float*)d_in[12];
    const float* b_lh = (const float*)d_in[13];
    const float* g_l = (const float*)d_in[14];
    const float* be_l = (const float*)d_in[15];
    const float* g_h = (const float*)d_in[16];
    const float* be_h = (const float*)d_in[17];
    const int* ei_ll = (const int*)d_in[18];
    const int* ei_hh = (const int*)d_in[19];
    const int* ei_hl = (const int*)d_in[20];
    const int* ei_lh = (const int*)d_in[21];

    char* p = (char*)d_ws;
    auto alloc = [&](size_t bytes) -> void* {
        void* r = (void*)p;
        p += (bytes + 255) & ~(size_t)255;
        return r;
    };
    const size_t HFEAT = (size_t)NN * 32 * sizeof(__half);
    const size_t FFEAT = (size_t)NN * 32 * sizeof(float);
    int2* pairs = (int2*)alloc((size_t)4 * EDG * sizeof(int2));
    float* new_l = (float*)pairs;
    float* new_h = (float*)((char*)pairs + FFEAT);
    __half* hgcn_l = (__half*)alloc(HFEAT);
    __half* hgcn_h = (__half*)alloc(HFEAT);
    __half* hgl_hl = (__half*)alloc(HFEAT);
    __half* hgr_hl = (__half*)alloc(HFEAT);
    __half* hgl_lh = (__half*)alloc(HFEAT);
    __half* hgr_lh = (__half*)alloc(HFEAT);
    int* cs = (int*)alloc((size_t)4 * EDG * sizeof(int));
    int* rp = (int*)alloc((size_t)4 * (NN + 1) * sizeof(int));
    float* dinv_l = (float*)alloc(NN * sizeof(float));
    float* dinv_h = (float*)alloc(NN * sizeof(float));
    int* bhist = (int*)alloc(4 * BKTPAD * sizeof(int));
    int* bases = (int*)alloc(4 * BKTPAD * sizeof(int));
    int* gcursor = (int*)alloc(4 * BKTPAD * sizeof(int));
    float* stats = (float*)alloc(4 * 64 * sizeof(float));

    const int TB = 256;
    k_init<<<2, TB, 0, stream>>>(bhist, stats);
    k_bhist<<<4 * CPR, TB, 0, stream>>>(ei_ll, ei_hh, ei_hl, ei_lh, bhist);
    k_bscan<<<1, TB, 0, stream>>>(bhist, bases, gcursor, rp);
    k_partition<<<4 * CPR, TB, 0, stream>>>(ei_ll, ei_hh, ei_hl, ei_lh, gcursor, pairs);
    k_build<<<4 * NBKT, TB, 0, stream>>>(pairs, bases, bhist, rp, cs);
    k_dinv<<<cdiv(2 * NN, TB), TB, 0, stream>>>(rp, dinv_l, dinv_h);

    const int* rp0 = rp;
    const int* rp1 = rp + (NN + 1);
    const int* rp2 = rp + 2 * (NN + 1);
    const int* rp3 = rp + 3 * (NN + 1);
    const int* cs0 = cs;
    const int* cs1 = cs + (size_t)EDG;
    const int* cs2 = cs + (size_t)2 * EDG;
    const int* cs3 = cs + (size_t)3 * EDG;

    const int GRID = 2048;
    float* st0l = stats;
    float* st0h = stats + 64;
    float* st1l = stats + 128;
    float* st1h = stats + 192;

    // ---- layer 0 ----
    k_gemm3<<<GRID, TB, 0, stream>>>(x_l, nullptr, nullptr, nullptr, Wll, Whl_r, Wlh_l, dinv_l,
                                     hgcn_l, hgr_hl, hgl_lh);
    k_gemm3<<<GRID, TB, 0, stream>>>(x_h, nullptr, nullptr, nullptr, Whh, Wlh_r, Whl_l, dinv_h,
                                     hgcn_h, hgr_lh, hgl_hl);
    k_aggregate<<<GRID, TB, 0, stream>>>(rp0, cs0, hgcn_l, dinv_l, rp2, cs2, hgl_hl, hgr_hl,
                                         att_hl, bll, b_hl, new_l, st0l);
    k_aggregate<<<GRID, TB, 0, stream>>>(rp1, cs1, hgcn_h, dinv_h, rp3, cs3, hgl_lh, hgr_lh,
                                         att_lh, bhh, b_lh, new_h, st0h);
    // ---- layer 1 (BN+ReLU of layer-0 fused into GEMM input load) ----
    k_gemm3<<<GRID, TB, 0, stream>>>(new_l, st0l, g_l, be_l, Wll + 1024, Whl_r + 1024,
                                     Wlh_l + 1024, dinv_l, hgcn_l, hgr_hl, hgl_lh);
    k_gemm3<<<GRID, TB, 0, stream>>>(new_h, st0h, g_h, be_h, Whh + 1024, Wlh_r + 1024,
                                     Whl_l + 1024, dinv_h, hgcn_h, hgr_lh, hgl_hl);
    k_aggregate<<<GRID, TB, 0, stream>>>(rp0, cs0, hgcn_l, dinv_l, rp2, cs2, hgl_hl, hgr_hl,
                                         att_hl + 32, bll + 32, b_hl + 32, new_l, st1l);
    k_aggregate<<<GRID, TB, 0, stream>>>(rp1, cs1, hgcn_h, dinv_h, rp3, cs3, hgl_lh, hgr_lh,
                                         att_lh + 32, bhh + 32, b_lh + 32, new_h, st1h);
    // ---- final BN + ReLU -> d_out ----
    k_bn_apply<<<GRID, TB, 0, stream>>>(new_l, st1l, g_l + 32, be_l + 32, (float*)d_out);
    k_bn_apply<<<GRID, TB, 0, stream>>>(new_h, st1h, g_h + 32, be_h + 32,
                                        ((float*)d_out) + (size_t)NN * 32);
}

// Round 11
// 679.178 us; speedup vs baseline: 1.7252x; 1.7252x over previous
//
#include <hip/hip_runtime.h>
#include <hip/hip_fp16.h>

#define NN 100000
#define EDG 1600000
#define LAY 2
#define NBKT 98      // ceil(NN / 1024)
#define BKTPAD 128
#define CAP 18432    // LDS sort capacity per bucket (avg 16384, ~16 sigma margin)
#define PCHUNK 2560  // edges per partition block (256 thr x 10)
#define CPR 625      // EDG / PCHUNK (exact)

static inline int cdiv(int a, int b) { return (a + b - 1) / b; }

// ---------------- init ----------------
__global__ void k_init(int* bhist, float* stats) {
    int t = blockIdx.x * blockDim.x + threadIdx.x;
    if (t < 4 * BKTPAD) bhist[t] = 0;
    if (t < 4 * 64) stats[t] = 0.f;
}

// ---------------- coarse bucket histogram ----------------
__global__ __launch_bounds__(256) void k_bhist(const int* __restrict__ ll,
                                               const int* __restrict__ hh,
                                               const int* __restrict__ hl,
                                               const int* __restrict__ lh, int* __restrict__ bhist) {
    __shared__ int h[NBKT];
    int tid = threadIdx.x;
    if (tid < NBKT) h[tid] = 0;
    __syncthreads();
    int r = blockIdx.x / CPR;
    int chunk = blockIdx.x - r * CPR;
    const int* dst = (r == 0 ? ll : r == 1 ? hh : r == 2 ? hl : lh) + EDG;
    int base = chunk * PCHUNK;
#pragma unroll
    for (int k = 0; k < 10; k++) {
        int d = dst[base + k * 256 + tid];
        atomicAdd(&h[d >> 10], 1);
    }
    __syncthreads();
    if (tid < NBKT) atomicAdd(&bhist[r * BKTPAD + tid], h[tid]);
}

// ---------------- tiny scan of bucket counts ----------------
__global__ void k_bscan(const int* __restrict__ bhist, int* __restrict__ bases,
                        int* __restrict__ gcursor, int* __restrict__ rp) {
    __shared__ int sh[BKTPAD];
    int t = threadIdx.x;
    for (int r = 0; r < 4; r++) {
        int v = (t < BKTPAD) ? ((t < NBKT) ? bhist[r * BKTPAD + t] : 0) : 0;
        if (t < BKTPAD) sh[t] = v;
        __syncthreads();
        for (int off = 1; off < BKTPAD; off <<= 1) {
            int x = (t < BKTPAD && t >= off) ? sh[t - off] : 0;
            __syncthreads();
            if (t < BKTPAD) sh[t] += x;
            __syncthreads();
        }
        if (t < BKTPAD) {
            int ex = sh[t] - v;
            bases[r * BKTPAD + t] = ex;
            gcursor[r * BKTPAD + t] = ex;
        }
        __syncthreads();
    }
    if (t < 4) rp[t * (NN + 1) + NN] = EDG;
}

// ---------------- partition edges into coarse buckets (coalesced runs) ----------------
__global__ __launch_bounds__(256) void k_partition(const int* __restrict__ ll,
                                                   const int* __restrict__ hh,
                                                   const int* __restrict__ hl,
                                                   const int* __restrict__ lh,
                                                   int* __restrict__ gcursor,
                                                   int2* __restrict__ pairs) {
    __shared__ int lhist[NBKT], lbase[NBKT];
    int tid = threadIdx.x;
    if (tid < NBKT) lhist[tid] = 0;
    __syncthreads();
    int r = blockIdx.x / CPR;
    int chunk = blockIdx.x - r * CPR;
    const int* ei = (r == 0 ? ll : r == 1 ? hh : r == 2 ? hl : lh);
    const int* srcp = ei;
    const int* dstp = ei + EDG;
    int base = chunk * PCHUNK;
    int s[10], d[10], rk[10];
#pragma unroll
    for (int k = 0; k < 10; k++) {
        int e = base + k * 256 + tid;
        s[k] = srcp[e];
        d[k] = dstp[e];
        rk[k] = atomicAdd(&lhist[d[k] >> 10], 1);
    }
    __syncthreads();
    if (tid < NBKT) lbase[tid] = atomicAdd(&gcursor[r * BKTPAD + tid], lhist[tid]);
    __syncthreads();
    int2* pr = pairs + (size_t)r * EDG;
#pragma unroll
    for (int k = 0; k < 10; k++) {
        int b = d[k] >> 10;
        pr[lbase[b] + rk[k]] = make_int2(s[k], d[k]);
    }
}

// ---------------- per-bucket CSR finalize: rowptr + coalesced cs ----------------
__global__ __launch_bounds__(256) void k_build(const int2* __restrict__ pairs,
                                               const int* __restrict__ bases,
                                               const int* __restrict__ bhist, int* __restrict__ rp,
                                               int* __restrict__ cs) {
    __shared__ int cnt_arr[1024];
    __shared__ int sh[256];
    __shared__ int srcs[CAP];
    int tid = threadIdx.x;
    int r = blockIdx.x / NBKT;
    int b = blockIdx.x - r * NBKT;
    int base = bases[r * BKTPAD + b];
    int cnt = bhist[r * BKTPAD + b];
    int d0 = b << 10;
    int ndst = NN - d0;
    if (ndst > 1024) ndst = 1024;
#pragma unroll
    for (int j = 0; j < 4; j++) cnt_arr[4 * tid + j] = 0;
    __syncthreads();
    const int2* pr = pairs + (size_t)r * EDG + base;
    for (int i = tid; i < cnt; i += 256) {
        int2 p = pr[i];
        atomicAdd(&cnt_arr[p.y - d0], 1);
    }
    __syncthreads();
    int c0 = cnt_arr[4 * tid], c1 = cnt_arr[4 * tid + 1], c2 = cnt_arr[4 * tid + 2],
        c3 = cnt_arr[4 * tid + 3];
    int s = c0 + c1 + c2 + c3;
    sh[tid] = s;
    __syncthreads();
    for (int off = 1; off < 256; off <<= 1) {
        int x = (tid >= off) ? sh[tid - off] : 0;
        __syncthreads();
        sh[tid] += x;
        __syncthreads();
    }
    int run = sh[tid] - s;
    int st0 = run, st1 = st0 + c0, st2 = st1 + c1, st3 = st2 + c2;
    cnt_arr[4 * tid] = st0;
    cnt_arr[4 * tid + 1] = st1;
    cnt_arr[4 * tid + 2] = st2;
    cnt_arr[4 * tid + 3] = st3;
    int* rpr = rp + r * (NN + 1);
    if (4 * tid + 0 < ndst) rpr[d0 + 4 * tid + 0] = base + st0;
    if (4 * tid + 1 < ndst) rpr[d0 + 4 * tid + 1] = base + st1;
    if (4 * tid + 2 < ndst) rpr[d0 + 4 * tid + 2] = base + st2;
    if (4 * tid + 3 < ndst) rpr[d0 + 4 * tid + 3] = base + st3;
    __syncthreads();
    for (int i = tid; i < cnt; i += 256) {
        int2 p = pr[i];
        int pos = atomicAdd(&cnt_arr[p.y - d0], 1);
        if (pos < CAP) srcs[pos] = p.x;
    }
    __syncthreads();
    int* csr = cs + (size_t)r * EDG + base;
    for (int i = tid; i < cnt; i += 256) csr[i] = (i < CAP) ? srcs[i] : 0;
}

__global__ void k_dinv(const int* __restrict__ rp, float* __restrict__ dinv_l,
                       float* __restrict__ dinv_h) {
    int i = blockIdx.x * blockDim.x + threadIdx.x;
    if (i >= 2 * NN) return;
    int r = (i < NN) ? 0 : 1, j = (i < NN) ? i : i - NN;
    const int* rpr = rp + r * (NN + 1);
    float deg = (float)(rpr[j + 1] - rpr[j]) + 1.f;
    float v = rsqrtf(deg);
    if (r == 0) dinv_l[j] = v;
    else dinv_h[j] = v;
}

// ---------------- fused (optional BN+ReLU input) 3-output GEMM, y0 pre-scaled by dinv ----------------
__global__ __launch_bounds__(256) void k_gemm3(const float* __restrict__ x,
                                               const float* __restrict__ stats,
                                               const float* __restrict__ gamma,
                                               const float* __restrict__ beta,
                                               const float* __restrict__ W0,
                                               const float* __restrict__ W1,
                                               const float* __restrict__ W2,
                                               const float* __restrict__ scale0,
                                               __half* __restrict__ y0, __half* __restrict__ y1,
                                               __half* __restrict__ y2) {
    __shared__ float Ws[3][1024];
    __shared__ float xs[8][32];
    int tid = threadIdx.x;
    for (int i = tid; i < 1024; i += 256) {
        Ws[0][i] = W0[i];
        Ws[1][i] = W1[i];
        Ws[2][i] = W2[i];
    }
    int c = tid & 31, rl = tid >> 5;
    float mu = 0.f, gs = 1.f, be = 0.f;
    if (stats) {
        const float inv_n = 1.f / (float)NN;
        mu = stats[c] * inv_n;
        float var = stats[32 + c] * inv_n - mu * mu;
        gs = gamma[c] * rsqrtf(var + 1e-5f);
        be = beta[c];
    }
    for (int r0 = blockIdx.x * 8; r0 < NN; r0 += gridDim.x * 8) {
        int r = r0 + rl;
        __syncthreads();
        if (r < NN) {
            float xv = x[(size_t)r * 32 + c];
            if (stats) {
                xv = gs * (xv - mu) + be;
                xv = (xv > 0.f) ? xv : 0.f;
            }
            xs[rl][c] = xv;
        }
        __syncthreads();
        if (r < NN) {
            float a0 = 0.f, a1 = 0.f, a2 = 0.f;
#pragma unroll
            for (int k = 0; k < 32; k++) {
                float xv = xs[rl][k];
                a0 += xv * Ws[0][k * 32 + c];
                a1 += xv * Ws[1][k * 32 + c];
                a2 += xv * Ws[2][k * 32 + c];
            }
            a0 *= scale0[r];
            y0[(size_t)r * 32 + c] = __float2half(a0);
            y1[(size_t)r * 32 + c] = __float2half(a1);
            y2[(size_t)r * 32 + c] = __float2half(a2);
        }
    }
}

// ---------------- fused GCN + GATv2 pull aggregation + BN-stats epilogue ----------------
// 4-lane groups: lane c4 owns 8 columns; each gather = global_load_dwordx4 (16B/lane,
// 64B/edge, 16 edges per wave-level load instruction)
__device__ inline void cvt8(int4 r, float2* f) {
    const __half2* h = (const __half2*)&r;
    f[0] = __half22float2(h[0]);
    f[1] = __half22float2(h[1]);
    f[2] = __half22float2(h[2]);
    f[3] = __half22float2(h[3]);
}

__global__ __launch_bounds__(256) void k_aggregate(
    const int* __restrict__ rp_gcn, const int* __restrict__ cs_gcn,
    const __half* __restrict__ h_gcn, const float* __restrict__ dinv,
    const int* __restrict__ rp_gat, const int* __restrict__ cs_gat,
    const __half* __restrict__ h_gl, const __half* __restrict__ h_gr,
    const float* __restrict__ attv, const float* __restrict__ b_gcn,
    const float* __restrict__ b_gat, float* __restrict__ out, float* __restrict__ stats) {
    int tid = threadIdx.x;
    int c4 = tid & 3;   // quad lane: cols [8*c4, 8*c4+8)
    int g = tid >> 2;   // 64 groups per block
    int v = blockIdx.x * 64 + g;
    bool alive = v < NN;

    const int4* hg4 = (const int4*)h_gcn;
    const int4* hl4 = (const int4*)h_gl;
    const int4* hr4p = (const int4*)h_gr;
    const float2* at2 = (const float2*)attv;

    float2 a[4];
#pragma unroll
    for (int q = 0; q < 4; q++) a[q] = at2[c4 * 4 + q];

    float2 res[4];
#pragma unroll
    for (int q = 0; q < 4; q++) res[q] = make_float2(0.f, 0.f);

    if (alive) {
        const int4 zero4 = make_int4(0, 0, 0, 0);
        // ---- GCN (rows pre-scaled by dinv[src]; self row pre-scaled too) ----
        float2 acc[4];
#pragma unroll
        for (int q = 0; q < 4; q++) acc[q] = make_float2(0.f, 0.f);
        int b0 = rp_gcn[v], e0 = rp_gcn[v + 1];
        for (int e = b0; e < e0; e += 4) {
            int myi = cs_gcn[min(e + c4, e0 - 1)];
            int4 raw[4];
#pragma unroll
            for (int j = 0; j < 4; j++) {
                int sj = __shfl(myi, j, 4);
                raw[j] = ((e + j) < e0) ? hg4[(size_t)sj * 4 + c4] : zero4;
            }
#pragma unroll
            for (int j = 0; j < 4; j++) {
                float2 f[4];
                cvt8(raw[j], f);
#pragma unroll
                for (int q = 0; q < 4; q++) {
                    acc[q].x += f[q].x;
                    acc[q].y += f[q].y;
                }
            }
        }
        {
            int4 selfr = hg4[(size_t)v * 4 + c4];
            float2 f[4];
            cvt8(selfr, f);
#pragma unroll
            for (int q = 0; q < 4; q++) {
                acc[q].x += f[q].x;
                acc[q].y += f[q].y;
            }
        }
        float dv = dinv[v];
        // ---- GATv2 online softmax, 4-edge chunks ----
        float2 hr[4];
        {
            int4 rr = hr4p[(size_t)v * 4 + c4];
            cvt8(rr, hr);
        }
        float m = -3.0e38f, ss = 0.f;
        float2 o[4];
#pragma unroll
        for (int q = 0; q < 4; q++) o[q] = make_float2(0.f, 0.f);
        int b1 = rp_gat[v], e1 = rp_gat[v + 1];
        for (int e = b1; e < e1; e += 4) {
            int myi = cs_gat[min(e + c4, e1 - 1)];
            int4 raw[4];
#pragma unroll
            for (int j = 0; j < 4; j++) {
                int sj = __shfl(myi, j, 4);
                raw[j] = hl4[(size_t)sj * 4 + c4];  // clamped idx: weight 0 if invalid
            }
            float p[4];
#pragma unroll
            for (int j = 0; j < 4; j++) {
                float2 f[4];
                cvt8(raw[j], f);
                float pj = 0.f;
#pragma unroll
                for (int q = 0; q < 4; q++) {
                    float tx = f[q].x + hr[q].x;
                    tx = (tx > 0.f) ? tx : 0.2f * tx;
                    float ty = f[q].y + hr[q].y;
                    ty = (ty > 0.f) ? ty : 0.2f * ty;
                    pj += tx * a[q].x + ty * a[q].y;
                }
                p[j] = pj;
            }
#pragma unroll
            for (int off = 1; off <= 2; off <<= 1) {
#pragma unroll
                for (int j = 0; j < 4; j++) p[j] += __shfl_xor(p[j], off, 4);
            }
#pragma unroll
            for (int j = 0; j < 4; j++)
                if ((e + j) >= e1) p[j] = -3.0e38f;
            float cmax = fmaxf(fmaxf(p[0], p[1]), fmaxf(p[2], p[3]));
            float mn = fmaxf(m, cmax);
            float sc = __expf(m - mn);
            float wsum = 0.f;
            float2 oa[4];
#pragma unroll
            for (int q = 0; q < 4; q++) oa[q] = make_float2(0.f, 0.f);
#pragma unroll
            for (int j = 0; j < 4; j++) {
                float w = __expf(p[j] - mn);
                wsum += w;
                float2 f[4];
                cvt8(raw[j], f);
#pragma unroll
                for (int q = 0; q < 4; q++) {
                    oa[q].x += w * f[q].x;
                    oa[q].y += w * f[q].y;
                }
            }
            ss = ss * sc + wsum;
#pragma unroll
            for (int q = 0; q < 4; q++) {
                o[q].x = o[q].x * sc + oa[q].x;
                o[q].y = o[q].y * sc + oa[q].y;
            }
            m = mn;
        }
        float inv = 1.f / (ss + 1e-16f);
#pragma unroll
        for (int q = 0; q < 4; q++) {
            float bx = b_gcn[c4 * 8 + 2 * q] + b_gat[c4 * 8 + 2 * q];
            float by = b_gcn[c4 * 8 + 2 * q + 1] + b_gat[c4 * 8 + 2 * q + 1];
            res[q].x = acc[q].x * dv + o[q].x * inv + bx;
            res[q].y = acc[q].y * dv + o[q].y * inv + by;
        }
        float4* o4 = (float4*)(out + (size_t)v * 32 + c4 * 8);
        o4[0] = make_float4(res[0].x, res[0].y, res[1].x, res[1].y);
        o4[1] = make_float4(res[2].x, res[2].y, res[3].x, res[3].y);
    }
    // ---- BN stats: wave butterfly over the 16 groups, then LDS, then global atomics ----
    float s1[8], s2[8];
#pragma unroll
    for (int q = 0; q < 4; q++) {
        s1[2 * q] = res[q].x;
        s1[2 * q + 1] = res[q].y;
        s2[2 * q] = res[q].x * res[q].x;
        s2[2 * q + 1] = res[q].y * res[q].y;
    }
#pragma unroll
    for (int off = 4; off <= 32; off <<= 1) {
#pragma unroll
        for (int k = 0; k < 8; k++) {
            s1[k] += __shfl_xor(s1[k], off, 64);
            s2[k] += __shfl_xor(s2[k], off, 64);
        }
    }
    __shared__ float sst[4][2][32];
    int wave = tid >> 6, lane = tid & 63;
    if (lane < 4) {
#pragma unroll
        for (int k = 0; k < 8; k++) {
            sst[wave][0][lane * 8 + k] = s1[k];
            sst[wave][1][lane * 8 + k] = s2[k];
        }
    }
    __syncthreads();
    if (tid < 64) {
        int which = tid >> 5, col = tid & 31;
        float t = sst[0][which][col] + sst[1][which][col] + sst[2][which][col] +
                  sst[3][which][col];
        atomicAdd(&stats[which * 32 + col], t);
    }
}

// ---------------- final BN apply + ReLU (float4) ----------------
__global__ void k_bn_apply(const float* __restrict__ x, const float* __restrict__ stats,
                           const float* __restrict__ gamma, const float* __restrict__ beta,
                           float* __restrict__ y) {
    int total4 = NN * 8;  // NN*32/4
    const float inv_n = 1.f / (float)NN;
    const float4* x4 = (const float4*)x;
    float4* y4 = (float4*)y;
    for (int i = blockIdx.x * blockDim.x + threadIdx.x; i < total4; i += gridDim.x * blockDim.x) {
        int c0 = (i * 4) & 31;
        float4 v = x4[i];
        float r[4] = {v.x, v.y, v.z, v.w};
#pragma unroll
        for (int j = 0; j < 4; j++) {
            int c = c0 + j;
            float mu = stats[c] * inv_n;
            float var = stats[32 + c] * inv_n - mu * mu;
            float gs = gamma[c] * rsqrtf(var + 1e-5f);
            float t = gs * (r[j] - mu) + beta[c];
            r[j] = (t > 0.f) ? t : 0.f;
        }
        y4[i] = make_float4(r[0], r[1], r[2], r[3]);
    }
}

// ---------------- host ----------------
extern "C" void kernel_launch(void* const* d_in, const int* in_sizes, int n_in, void* d_out,
                              int out_size, void* d_ws, size_t ws_size, hipStream_t stream) {
    const float* x_l = (const float*)d_in[0];
    const float* x_h = (const float*)d_in[1];
    const float* Wll = (const float*)d_in[2];
    const float* bll = (const float*)d_in[3];
    const float* Whh = (const float*)d_in[4];
    const float* bhh = (const float*)d_in[5];
    const float* Whl_l = (const float*)d_in[6];
    const float* Whl_r = (const float*)d_in[7];
    const float* att_hl = (const float*)d_in[8];
    const float* b_hl = (const float*)d_in[9];
    const float* Wlh_l = (const float*)d_in[10];
    const float* Wlh_r = (const float*)d_in[11];
    const float* att_lh = (const float*)d_in[12];
    const float* b_lh = (const float*)d_in[13];
    const float* g_l = (const float*)d_in[14];
    const float* be_l = (const float*)d_in[15];
    const float* g_h = (const float*)d_in[16];
    const float* be_h = (const float*)d_in[17];
    const int* ei_ll = (const int*)d_in[18];
    const int* ei_hh = (const int*)d_in[19];
    const int* ei_hl = (const int*)d_in[20];
    const int* ei_lh = (const int*)d_in[21];

    char* p = (char*)d_ws;
    auto alloc = [&](size_t bytes) -> void* {
        void* r = (void*)p;
        p += (bytes + 255) & ~(size_t)255;
        return r;
    };
    const size_t HFEAT = (size_t)NN * 32 * sizeof(__half);
    const size_t FFEAT = (size_t)NN * 32 * sizeof(float);
    int2* pairs = (int2*)alloc((size_t)4 * EDG * sizeof(int2));
    float* new_l = (float*)pairs;
    float* new_h = (float*)((char*)pairs + FFEAT);
    __half* hgcn_l = (__half*)alloc(HFEAT);
    __half* hgcn_h = (__half*)alloc(HFEAT);
    __half* hgl_hl = (__half*)alloc(HFEAT);
    __half* hgr_hl = (__half*)alloc(HFEAT);
    __half* hgl_lh = (__half*)alloc(HFEAT);
    __half* hgr_lh = (__half*)alloc(HFEAT);
    int* cs = (int*)alloc((size_t)4 * EDG * sizeof(int));
    int* rp = (int*)alloc((size_t)4 * (NN + 1) * sizeof(int));
    float* dinv_l = (float*)alloc(NN * sizeof(float));
    float* dinv_h = (float*)alloc(NN * sizeof(float));
    int* bhist = (int*)alloc(4 * BKTPAD * sizeof(int));
    int* bases = (int*)alloc(4 * BKTPAD * sizeof(int));
    int* gcursor = (int*)alloc(4 * BKTPAD * sizeof(int));
    float* stats = (float*)alloc(4 * 64 * sizeof(float));

    const int TB = 256;
    k_init<<<2, TB, 0, stream>>>(bhist, stats);
    k_bhist<<<4 * CPR, TB, 0, stream>>>(ei_ll, ei_hh, ei_hl, ei_lh, bhist);
    k_bscan<<<1, TB, 0, stream>>>(bhist, bases, gcursor, rp);
    k_partition<<<4 * CPR, TB, 0, stream>>>(ei_ll, ei_hh, ei_hl, ei_lh, gcursor, pairs);
    k_build<<<4 * NBKT, TB, 0, stream>>>(pairs, bases, bhist, rp, cs);
    k_dinv<<<cdiv(2 * NN, TB), TB, 0, stream>>>(rp, dinv_l, dinv_h);

    const int* rp0 = rp;
    const int* rp1 = rp + (NN + 1);
    const int* rp2 = rp + 2 * (NN + 1);
    const int* rp3 = rp + 3 * (NN + 1);
    const int* cs0 = cs;
    const int* cs1 = cs + (size_t)EDG;
    const int* cs2 = cs + (size_t)2 * EDG;
    const int* cs3 = cs + (size_t)3 * EDG;

    const int GRID = 2048;
    const int AGRID = cdiv(NN, 64);
    float* st0l = stats;
    float* st0h = stats + 64;
    float* st1l = stats + 128;
    float* st1h = stats + 192;

    // ---- layer 0 ----
    k_gemm3<<<GRID, TB, 0, stream>>>(x_l, nullptr, nullptr, nullptr, Wll, Whl_r, Wlh_l, dinv_l,
                                     hgcn_l, hgr_hl, hgl_lh);
    k_gemm3<<<GRID, TB, 0, stream>>>(x_h, nullptr, nullptr, nullptr, Whh, Wlh_r, Whl_l, dinv_h,
                                     hgcn_h, hgr_lh, hgl_hl);
    k_aggregate<<<AGRID, TB, 0, stream>>>(rp0, cs0, hgcn_l, dinv_l, rp2, cs2, hgl_hl, hgr_hl,
                                          att_hl, bll, b_hl, new_l, st0l);
    k_aggregate<<<AGRID, TB, 0, stream>>>(rp1, cs1, hgcn_h, dinv_h, rp3, cs3, hgl_lh, hgr_lh,
                                          att_lh, bhh, b_lh, new_h, st0h);
    // ---- layer 1 (BN+ReLU of layer-0 fused into GEMM input load) ----
    k_gemm3<<<GRID, TB, 0, stream>>>(new_l, st0l, g_l, be_l, Wll + 1024, Whl_r + 1024,
                                     Wlh_l + 1024, dinv_l, hgcn_l, hgr_hl, hgl_lh);
    k_gemm3<<<GRID, TB, 0, stream>>>(new_h, st0h, g_h, be_h, Whh + 1024, Wlh_r + 1024,
                                     Whl_l + 1024, dinv_h, hgcn_h, hgr_lh, hgl_hl);
    k_aggregate<<<AGRID, TB, 0, stream>>>(rp0, cs0, hgcn_l, dinv_l, rp2, cs2, hgl_hl, hgr_hl,
                                          att_hl + 32, bll + 32, b_hl + 32, new_l, st1l);
    k_aggregate<<<AGRID, TB, 0, stream>>>(rp1, cs1, hgcn_h, dinv_h, rp3, cs3, hgl_lh, hgr_lh,
                                          att_lh + 32, bhh + 32, b_lh + 32, new_h, st1h);
    // ---- final BN + ReLU -> d_out ----
    k_bn_apply<<<GRID, TB, 0, stream>>>(new_l, st1l, g_l + 32, be_l + 32, (float*)d_out);
    k_bn_apply<<<GRID, TB, 0, stream>>>(new_h, st1h, g_h + 32, be_h + 32,
                                        ((float*)d_out) + (size_t)NN * 32);
}